// Round 7
// baseline (146.130 us; speedup 1.0000x reference)
//
#include <hip/hip_runtime.h>

#define NC 19
#define NCPY 32           // rotating global copies of the 57 counters
#define CSLOT 64          // u32 stride per copy (57 used)
#define EPS 1e-5f
#define BS 256
#define KPT 8             // int4s per thread (32 elements -> 6-bit stage cap 63 OK)

typedef int v4i __attribute__((ext_vector_type(4)));

// Mask of ten 3-bit fields at 6-bit pitch (bits 6k..6k+2, k=0..9).
#define ME 0x01C71C71C71C71C7ULL

// Full-wave (64-lane) sum on the VALU pipe via DPP; lane 63 holds the total.
__device__ __forceinline__ unsigned wave_sum_dpp(unsigned v) {
    v += (unsigned)__builtin_amdgcn_update_dpp(0, (int)v, 0x111, 0xF, 0xF, true); // row_shr:1
    v += (unsigned)__builtin_amdgcn_update_dpp(0, (int)v, 0x112, 0xF, 0xF, true); // row_shr:2
    v += (unsigned)__builtin_amdgcn_update_dpp(0, (int)v, 0x114, 0xF, 0xF, true); // row_shr:4
    v += (unsigned)__builtin_amdgcn_update_dpp(0, (int)v, 0x118, 0xF, 0xF, true); // row_shr:8
    v += (unsigned)__builtin_amdgcn_update_dpp(0, (int)v, 0x142, 0xA, 0xF, true); // row_bcast:15 -> rows 1,3
    v += (unsigned)__builtin_amdgcn_update_dpp(0, (int)v, 0x143, 0xC, 0xF, true); // row_bcast:31 -> rows 2,3
    return v;
}

// Kernel 1: counts via in-REGISTER packed histograms (no LDS in hot loop —
// the ds_atomic pipe was the measured ~33 us floor; this moves counting to
// the ~75%-idle VALU). 19 classes x 3 bits = 57 <= 64: indexed increment is
// `1ULL << 3*t`. Pyramid: 3-bit (<=4/int4) -> 6-bit even/odd (<=32/thread)
// -> u16-packed DPP wave-reduce (<=2048 per field). Exact at every level.
__global__ __launch_bounds__(BS) void count_kernel(
    const v4i* __restrict__ yp, const v4i* __restrict__ yt,
    unsigned int* __restrict__ gJ, int n4)
{
    const int tid = threadIdx.x;
    const int nth = (int)gridDim.x * BS;
    const int base = (int)blockIdx.x * BS + tid;

    // Issue all 16 nontemporal loads up front (R5-proven read path).
    // Invalid slots get sentinel class 19 -> bits 57-59 (even) / SO field k=9
    // (odd path) -> never read at extraction.
    v4i P[KPT], T[KPT];
    #pragma unroll
    for (int u = 0; u < KPT; ++u) {
        const int idx = base + u * nth;
        if (idx < n4) {
            P[u] = __builtin_nontemporal_load(&yp[idx]);
            T[u] = __builtin_nontemporal_load(&yt[idx]);
        } else {
            P[u] = (v4i){NC, NC, NC, NC};
            T[u] = (v4i){NC, NC, NC, NC};
        }
    }

    unsigned long long St = 0, Sp = 0, Si = 0;                    // 3-bit stage
    unsigned long long SEt = 0, SOt = 0, SEp = 0, SOp = 0,        // 6-bit stage
                       SEi = 0, SOi = 0;

#define UPD(tt, pp) {                                              \
        const int t_ = (tt), p_ = (pp);                            \
        const unsigned long long ot = 1ULL << (3 * t_);            \
        St += ot;                                                  \
        Sp += 1ULL << (3 * p_);                                    \
        if (t_ == p_) Si += ot;                                    \
    }

    #pragma unroll
    for (int u = 0; u < KPT; ++u) {
        UPD(T[u].x, P[u].x)
        UPD(T[u].y, P[u].y)
        UPD(T[u].z, P[u].z)
        UPD(T[u].w, P[u].w)
        // flush 3-bit -> 6-bit (even classes at 6k in SE*, odd in SO*)
        SEt += St & ME; SOt += (St >> 3) & ME; St = 0;
        SEp += Sp & ME; SOp += (Sp >> 3) & ME; Sp = 0;
        SEi += Si & ME; SOi += (Si >> 3) & ME; Si = 0;
    }
#undef UPD

    // Extract 6-bit fields, pack two classes per u32 (bits 0 / 16):
    // pk[h*10+j] = class 2j | class 2j+1 << 16   (hist h: 0=t, 1=p, 2=inter)
    unsigned pk[30];
#define PACK(SE, SO, off) {                                        \
        _Pragma("unroll")                                          \
        for (int j = 0; j < 10; ++j) {                             \
            unsigned lo = (unsigned)(((SE) >> (6 * j)) & 63ULL);   \
            unsigned hi = (j < 9) ? (unsigned)(((SO) >> (6 * j)) & 63ULL) : 0u; \
            pk[(off) + j] = lo | (hi << 16);                       \
        }                                                          \
    }
    PACK(SEt, SOt, 0)
    PACK(SEp, SOp, 10)
    PACK(SEi, SOi, 20)
#undef PACK

    // Wave-reduce the 30 packed regs on the VALU pipe (fields <= 32*64 = 2048,
    // no cross-halfword carry). Lane 63 holds the wave totals.
    #pragma unroll
    for (int j = 0; j < 30; ++j) pk[j] = wave_sum_dpp(pk[j]);

    __shared__ unsigned sW[BS / 64][32];
    const int wave = tid >> 6, lane = tid & 63;
    if (lane == 63) {
        #pragma unroll
        for (int j = 0; j < 30; ++j) sW[wave][j] = pk[j];
    }
    __syncthreads();

    // Block combine + one device atomic per counter into a rotating copy.
    if (tid < 57) {
        const int h = tid / NC, c = tid % NC;
        const int sh = (c & 1) << 4, j = c >> 1;
        unsigned v = 0;
        #pragma unroll
        for (int w = 0; w < BS / 64; ++w)
            v += (sW[w][h * 10 + j] >> sh) & 0xFFFFu;
        atomicAdd(&gJ[(blockIdx.x & (NCPY - 1)) * CSLOT + tid], v);
    }
}

// Kernel 2: one wave. Sum the 32 copies; lanes 0..18 compute dice; reduce.
__global__ __launch_bounds__(64) void dice_final_kernel(
    const unsigned int* __restrict__ gJ, float* __restrict__ out)
{
    const int tid = threadIdx.x;
    __shared__ unsigned cnt[57];
    if (tid < 57) {
        unsigned s = 0;
        #pragma unroll
        for (int c = 0; c < NCPY; ++c) s += gJ[c * CSLOT + tid];
        cnt[tid] = s;
    }
    __syncthreads();

    float dice = 0.0f;
    if (tid < NC) {
        float ct = (float)cnt[tid];          // count_y
        float cp = (float)cnt[NC + tid];     // count_p
        float ci = (float)cnt[2 * NC + tid]; // intersection
        float uni = ct + cp - ci;
        dice = (2.0f * ci + EPS) / (uni + EPS);
    }
    #pragma unroll
    for (int off = 32; off > 0; off >>= 1)
        dice += __shfl_down(dice, off, 64);
    if (tid == 0) out[0] = 1.0f - dice / (float)NC;
}

extern "C" void kernel_launch(void* const* d_in, const int* in_sizes, int n_in,
                              void* d_out, int out_size, void* d_ws, size_t ws_size,
                              hipStream_t stream)
{
    const v4i* yp = (const v4i*)d_in[0];     // y_pred, int32
    const v4i* yt = (const v4i*)d_in[1];     // y,      int32
    unsigned int* gJ = (unsigned int*)d_ws;  // 32 copies x 64 u32 = 8 KB
    float* out = (float*)d_out;

    const int n = in_sizes[0];               // 16*1024*1024, divisible by 4
    const int n4 = n >> 2;

    // ws is poisoned before every timed launch — zero the 8 KB of counters.
    hipMemsetAsync(d_ws, 0, NCPY * CSLOT * sizeof(unsigned int), stream);

    // Exactly KPT int4s per thread (4M int4 / (2048*256) = 8 -> 32 el/thread,
    // the 6-bit stage capacity bound). Sentinel guard covers non-exact n.
    const int grid = (n4 + BS * KPT - 1) / (BS * KPT);

    count_kernel<<<grid, BS, 0, stream>>>(yp, yt, gJ, n4);
    dice_final_kernel<<<1, 64, 0, stream>>>(gJ, out);
}

// Round 8
// 143.455 us; speedup vs baseline: 1.0186x; 1.0186x over previous
//
#include <hip/hip_runtime.h>

#define NC 19
#define NB 361            // 19*19 joint-histogram bins
#define NCPY 32           // rotating global copies (tail chain depth 1024/32 = 32)
#define EPS 1e-5f
#define BS 256
#define GRID 1024         // 4 blocks/CU, 16 waves/CU; 16 iterations/thread
#define PFD 2             // prefetch distance (iterations ahead); ~2.1 MB/XCD in L2

typedef int v4i __attribute__((ext_vector_type(4)));

// Kernel 1: joint histogram J[t*19+p], R5's proven consumer (per-wave LDS
// atomic copies, nt loads) + ATOMIC-PREFETCH: streaming reads are pinned at
// ~34 lines x 128B / latency per CU (TCP in-flight cap); the only lever left
// is latency. A no-return atomicAdd(+0) on one dword per 128B line is
// fire-and-forget (store-like: the 6.6 TB/s fill proves such ops don't hold
// TCP slots) and executes at the TCC — if that's the XCD-local L2, the line
// becomes L2-resident and the real load 2 iterations later hits at ~200 cyc
// instead of ~700. Self-prefetch of each thread's own future address makes
// XCD placement automatically correct. +0 is value-identical => benign.
__global__ __launch_bounds__(BS, 4) void joint_hist_kernel(
    const v4i* __restrict__ yp, const v4i* __restrict__ yt,
    unsigned int* __restrict__ gJ, int n4)
{
    __shared__ unsigned int sJ[4 * NB];
    const int tid = threadIdx.x;
    unsigned int* mine = &sJ[(tid >> 6) * NB];   // per-wave private copy

    for (int i = tid; i < 4 * NB; i += BS) sJ[i] = 0u;
    __syncthreads();

    const int nth = (int)gridDim.x * BS;         // 262144 int4s per iteration
    const bool pf_lane = (tid & 7) == 0;         // one lane per 128B line (8 int4s)
    unsigned int* up = (unsigned int*)yp;        // +0 atomics: value-identical
    unsigned int* ut = (unsigned int*)yt;

    // Prologue: warm iterations 0..PFD-1 (fire-and-forget, never waited on).
    if (pf_lane) {
        #pragma unroll
        for (int d = 0; d < PFD; ++d) {
            const int j = (int)blockIdx.x * BS + tid + d * nth;
            if (j < n4) {
                atomicAdd(&up[4 * j], 0u);
                atomicAdd(&ut[4 * j], 0u);
            }
        }
    }

    for (int i = (int)blockIdx.x * BS + tid; i < n4; i += nth) {
        const v4i p = __builtin_nontemporal_load(&yp[i]);
        const v4i t = __builtin_nontemporal_load(&yt[i]);
        // Keep prefetch atomics AFTER the loads in issue order: vmcnt retires
        // in order, so waits for p/t never block on an atomic ack.
        __builtin_amdgcn_sched_barrier(0);
        const int j = i + PFD * nth;
        if (pf_lane && j < n4) {
            atomicAdd(&up[4 * j], 0u);           // lanes 0,8,..56: 8 distinct lines
            atomicAdd(&ut[4 * j], 0u);
        }
        atomicAdd(&mine[t.x * NC + p.x], 1u);
        atomicAdd(&mine[t.y * NC + p.y], 1u);
        atomicAdd(&mine[t.z * NC + p.z], 1u);
        atomicAdd(&mine[t.w * NC + p.w], 1u);
    }
    __syncthreads();

    // Reduce the 4 wave-copies; one device atomic per bin into this block's
    // rotating copy (1024/32 = 32-deep chains, ~1 us).
    unsigned int* myg = &gJ[(blockIdx.x & (NCPY - 1)) * NB];
    for (int b = tid; b < NB; b += BS) {
        unsigned int v = sJ[b] + sJ[NB + b] + sJ[2 * NB + b] + sJ[3 * NB + b];
        if (v) atomicAdd(&myg[b], v);
    }
}

// Kernel 2: one 512-thread block. Thread b (<361) sums bin b over the 32
// copies (46 KB, L2-resident); then wave 0 computes dice.
__global__ __launch_bounds__(512) void dice_final_kernel(
    const unsigned int* __restrict__ gJ, float* __restrict__ out)
{
    __shared__ unsigned int J[NB];
    const int tid = threadIdx.x;

    if (tid < NB) {
        unsigned int s = 0;
        #pragma unroll
        for (int c = 0; c < NCPY; ++c) s += gJ[c * NB + tid];
        J[tid] = s;
    }
    __syncthreads();

    if (tid < 64) {
        float dice = 0.0f;
        if (tid < NC) {
            float inter = (float)J[tid * NC + tid];
            float cy = 0.0f, cp = 0.0f;
            #pragma unroll
            for (int j = 0; j < NC; ++j) {
                cy += (float)J[tid * NC + j];
                cp += (float)J[j * NC + tid];
            }
            float uni = cy + cp - inter;
            dice = (2.0f * inter + EPS) / (uni + EPS);
        }
        #pragma unroll
        for (int off = 32; off > 0; off >>= 1)
            dice += __shfl_down(dice, off, 64);
        if (tid == 0) out[0] = 1.0f - dice / (float)NC;
    }
}

extern "C" void kernel_launch(void* const* d_in, const int* in_sizes, int n_in,
                              void* d_out, int out_size, void* d_ws, size_t ws_size,
                              hipStream_t stream)
{
    const v4i* yp = (const v4i*)d_in[0];     // y_pred, int32
    const v4i* yt = (const v4i*)d_in[1];     // y,      int32
    unsigned int* gJ = (unsigned int*)d_ws;  // 32 copies of 361 u32
    float* out = (float*)d_out;

    const int n = in_sizes[0];               // 16*1024*1024, divisible by 4
    const int n4 = n >> 2;

    // ws is poisoned before every timed launch — zero the 32 copies (46 KB).
    hipMemsetAsync(d_ws, 0, NCPY * NB * sizeof(unsigned int), stream);

    joint_hist_kernel<<<GRID, BS, 0, stream>>>(yp, yt, gJ, n4);
    dice_final_kernel<<<1, 512, 0, stream>>>(gJ, out);
}